// Round 3
// baseline (864.268 us; speedup 1.0000x reference)
//
#include <hip/hip_runtime.h>

// LocallyConnected2d: x [64,32,64,64] f32, w [1,64,32,62,62,9] f32 -> out [64,64,62,62] f32
// out[b,o,loc] = sum_{i,k} x[b,i,oh+k/3,ow+k%3] * w[o,i,loc,k]
//
// Round-3: weight is wave-uniform (lane=b) -> stream it through the SCALAR path
// (s_load_dwordx16 chains into SGPRs, zero VALU/LDS cost, used as the SGPR operand
// of v_fmac_f32). Round-2 died on LDS broadcast bandwidth (~12cyc per b128 even
// same-address). No LDS at all now.
//  - block = 4 output locs (one oh, 4 ow)  -> weight run per (o,i) = 36 contiguous
//    floats, scalar double-buffered one op ahead.
//  - lane = b, x read from pre-transposed xT[m][b]: coalesced 256B, identical across
//    all 8 waves -> L1-hot.
//  - out: 2x float2 per (b,o), consecutive-loc blocks chunked per XCD so L2 merges
//    partial lines.

#define OWDIM 62
#define LOCS 3844
#define XM 131072u   // 32*64*64 per-batch elements

__global__ void lc2d_transpose_x(const float* __restrict__ x, float* __restrict__ xT) {
    __shared__ float tile[64][65];
    const int m0 = blockIdx.x * 64;
    const int t = threadIdx.x;
    const int c = t & 63, q = t >> 6;   // q in 0..3
#pragma unroll
    for (int j = 0; j < 16; ++j) {
        const int b = q * 16 + j;
        tile[c][b] = x[(size_t)b * XM + (size_t)(m0 + c)];
    }
    __syncthreads();
#pragma unroll
    for (int j = 0; j < 16; ++j) {
        const int m = q * 16 + j;
        xT[(size_t)(m0 + m) * 64u + (size_t)c] = tile[m][c];
    }
}

__global__ __launch_bounds__(512, 4) void lc2d_main(const float* __restrict__ w,
                                                    const float* __restrict__ xT,
                                                    float* __restrict__ out) {
    // grid 992 = 62 oh * 16 ow-tiles; XCD-chunked bijective swizzle (992 = 8*124)
    const int bid = blockIdx.x;
    const int tile = (bid & 7) * 124 + (bid >> 3);
    const int oh = tile >> 4;
    const int t4 = tile & 15;
    const int ow0 = (t4 < 15) ? (t4 << 2) : 58;   // last tile overlaps -> no guards
    const int loc0 = oh * OWDIM + ow0;

    const int lane = threadIdx.x & 63;                                    // = b
    const int g = __builtin_amdgcn_readfirstlane((int)(threadIdx.x >> 6)); // o-group

    float acc[8][4];
#pragma unroll
    for (int a = 0; a < 8; ++a)
#pragma unroll
        for (int l = 0; l < 4; ++l) acc[a][l] = 0.f;

    float xrA[18], xrB[18];   // x taps, double-buffered across i (VGPR, per-lane)
    float wsP[36], wsQ[36];   // weight runs, double-buffered across op (SGPR stream)

    // uniform float-offset of the 36-float run for (o = g*8+op, i, loc0)
    auto woff = [&](int i, int op) -> int {
        const int o = g * 8 + op;
        return __builtin_amdgcn_readfirstlane(((o * 32 + i) * LOCS + loc0) * 9);
    };
    auto load36 = [&](float* ws, int off) {
        const float* p = w + (size_t)off;
#pragma unroll
        for (int j = 0; j < 36; ++j) ws[j] = p[j];   // uniform addr -> s_load_dwordx16 chain
    };
    auto loadx = [&](float* xr, int i) {
        const float* xp = xT + (((size_t)i * 4096u + (size_t)(oh * 64 + ow0)) << 6) + (size_t)lane;
#pragma unroll
        for (int r = 0; r < 3; ++r)
#pragma unroll
            for (int c = 0; c < 6; ++c)
                xr[r * 6 + c] = xp[(size_t)((r * 4096 + c * 64))];
    };

    // one octet = all 8 o's for channel i; scalar prefetch runs one op ahead
    auto octet = [&](int i, const float* xr) {
#pragma unroll
        for (int op = 0; op < 8; ++op) {
            const float* cur = (op & 1) ? wsQ : wsP;
            float* nxt = (op & 1) ? wsP : wsQ;
            const int ni = (op == 7) ? i + 1 : i;
            const int nop = (op + 1) & 7;
            if (ni < 32) load36(nxt, woff(ni, nop));
#pragma unroll
            for (int l = 0; l < 4; ++l)
#pragma unroll
                for (int k = 0; k < 9; ++k)
                    acc[op][l] = fmaf(cur[l * 9 + k], xr[(k / 3) * 6 + l + (k % 3)], acc[op][l]);
        }
    };

    load36(wsP, woff(0, 0));
    loadx(xrA, 0);

#pragma unroll 1
    for (int i = 0; i < 32; i += 2) {
        loadx(xrB, i + 1);
        octet(i, xrA);
        if (i + 2 < 32) loadx(xrA, i + 2);
        octet(i + 1, xrB);
    }

    // out[b][o][loc0..loc0+3]: 2x float2 per (b,o); loc0 even -> 8B aligned
#pragma unroll
    for (int op = 0; op < 8; ++op) {
        float* po = out + (size_t)(lane * 64 + g * 8 + op) * (size_t)LOCS + (size_t)loc0;
        *(float2*)(po + 0) = make_float2(acc[op][0], acc[op][1]);
        *(float2*)(po + 2) = make_float2(acc[op][2], acc[op][3]);
    }
}

extern "C" void kernel_launch(void* const* d_in, const int* in_sizes, int n_in,
                              void* d_out, int out_size, void* d_ws, size_t ws_size,
                              hipStream_t stream) {
    const float* x = (const float*)d_in[0];   // 64*32*64*64
    const float* w = (const float*)d_in[1];   // 1*64*32*62*62*9
    float* out = (float*)d_out;               // 64*64*62*62
    float* xT = (float*)d_ws;                 // 32 MiB scratch

    lc2d_transpose_x<<<dim3(XM / 64), dim3(256), 0, stream>>>(x, xT);
    lc2d_main<<<dim3(992), dim3(512), 0, stream>>>(w, xT, out);
}